// Round 21
// baseline (1087.566 us; speedup 1.0000x reference)
//
#include <hip/hip_runtime.h>
#include <hip/hip_fp16.h>
#include <cmath>

// DHT: out[n,c,a,r] = sum over px (x,y) of feat[n,c,y,x],
//   r = rint((x-128)*cos(a deg) + (y-128)*sin(a deg)) + 361  (r in [180,542])
// feat[4,128,256,256] f32 -> out[4,128,180,723] f32.
//
// Locked-in findings:
//  R1-R4: LDS f32 atomicAdd ~per-lane serial -> never on hot path.
//  R5/R18: program-ordered DS RMW race-free iff lanes' bins distinct PER
//    INSTRUCTION; no source-level read-hoisting across lane-overlapping
//    writes. R10: exec-masked DS poison.
//  R12/R15/R17/R20: SQ_LDS_BANK_CONFLICT = PORT-BYTE tax (prop. to RMW
//    bytes; invariant to addresses AND instruction width/count).
//  R17 (846us): f16 accum, 4 img/b64. R19 (813us, BEST): dual-angle
//    no-alias chains (+33us ILP). R20 (830us): b128/8-img null -> residue
//    is NOT per-instruction overhead.
//  Budget at R19: port 0.74M + byte-tax 0.54M + VALU 0.65M ~= wall 1.95M
//    -> VALU and DS serialized within each wave's dependent chain; only
//    4 waves/SIMD (94KB LDS -> 1 block/CU) to overlap them.
//  R21: CH=1 -> 47KB LDS -> 2 blocks/CU = 32 waves (8/SIMD, max). Trades
//    dual-chain ILP for 2x wave-level overlap. Same port bytes, same
//    per-angle zero/flush volume, same 2-contrib atomics.

#define NA 180
#define NR 723
#define HW 65536
#define NC 512
#define ROW_W 368       // bins rl = r-RBASE in [4,366]
#define ROW_PAD 368
#define RBASE 176
#define NWIN 32         // 8-px windows along the scan axis

__device__ __forceinline__ bool is_phase2(int a) { return a >= 46 && a <= 134; }

// 4 images packed per bin: .a = {img0,img1}, .b = {img2,img3}
struct __align__(8) h4 { __half2 a, b; };

// ---------------------------------------------------------------------------
// win[a][w][fast] u32 = base bin at scan=8w (bits 0..15), step bits 16..22.
// Phase-1 (a in [0,45]u[135,179]): fast=x, scan=y. Phase-2 (a in [46,134]):
// fast=y, scan=x (sign flips at 90). fp64 non-fused + rint == np.round
// (validated R1-R20).
// ---------------------------------------------------------------------------
__global__ __launch_bounds__(256) void dht_win(unsigned int* __restrict__ win) {
    const int lane = threadIdx.x;
    const int w = blockIdx.x;
    const int a = blockIdx.y;
    const double theta = (double)a * (M_PI / 180.0);
    const double c = cos(theta), s = sin(theta);
    const bool p2 = is_phase2(a);
    int prev = 0;
    unsigned int word = 0;
    #pragma unroll
    for (int i = 0; i < 8; ++i) {
        const int k = w * 8 + i;
        const int x = p2 ? k : lane;
        const int y = p2 ? lane : k;
        const double rho = __dadd_rn(__dmul_rn((double)(x - 128), c),
                                     __dmul_rn((double)(y - 128), s));
        int r = (int)rint(rho) + 361;
        r = min(max(r, 0), NR - 1);
        if (i == 0) word = (unsigned int)r;
        else if (r != prev) word |= (1u << (15 + i));
        prev = r;
    }
    win[((size_t)a * NWIN + w) * 256 + lane] = word;
}

__global__ __launch_bounds__(256) void zero_out(float4* __restrict__ o, int n4) {
    const int i = blockIdx.x * 256 + threadIdx.x;
    if (i < n4) o[i] = make_float4(0.f, 0.f, 0.f, 0.f);
}

// Single-angle walk (R17 form): strict per-visit read->add->write order;
// lanes 2 cols apart -> bins >= 1.414 apart per instruction -> race-free.
template <int SGN>
__device__ __forceinline__ void walk_one(const uint4 wq,
                                         const __half2 (&pxA)[8][4],
                                         const __half2 (&pxB)[8][4],
                                         h4* __restrict__ rp) {
    #pragma unroll
    for (int j = 0; j < 4; ++j) {
        const unsigned int wrd = (&wq.x)[j];
        int bin = (int)(wrd & 0xffffu) - RBASE;
        #pragma unroll
        for (int k = 0; k < 8; ++k) {
            if (k) bin += SGN * (int)((wrd >> (15 + k)) & 1u);
            h4 v = rp[bin];
            v.a = __hadd2(v.a, pxA[k][j]);
            v.b = __hadd2(v.b, pxB[k][j]);
            rp[bin] = v;
        }
    }
}

// ---------------------------------------------------------------------------
// Block = (image-quad, phase, scan-half). 1024 thr = 16 waves; wave wv owns
// scan window w = 16h+wv (8 scan lines); lane owns fast columns
// {2l, 2l+1, 2l+128, 2l+129} (j = 0..3). px as __half2 pairs (64 VGPR),
// loaded+converted ONCE, reused across all angles of the phase.
// rows[16 waves][ROW_PAD] h4 = 47.1 KB -> 2 blocks/CU = 32 waves (8/SIMD).
// ---------------------------------------------------------------------------
__global__ __launch_bounds__(1024, 8) void dht_main(const float* __restrict__ feat,
                                                    const unsigned int* __restrict__ win,
                                                    float* __restrict__ out) {
    __shared__ h4 rows[16 * ROW_PAD];   // 47.1 KB, one angle at a time
    const int t = threadIdx.x;
    const int wv = t >> 6;
    const int l = t & 63;
    const int quad = blockIdx.x;
    const int phase = blockIdx.y;
    const int h = blockIdx.z;
    const int w = 16 * h + wv;          // scan window 0..31
    const int k0 = 8 * w;               // scan offset
    const float* __restrict__ f0 = feat + (size_t)(4 * quad + 0) * HW;
    const float* __restrict__ f1 = feat + (size_t)(4 * quad + 1) * HW;
    const float* __restrict__ f2 = feat + (size_t)(4 * quad + 2) * HW;
    const float* __restrict__ f3 = feat + (size_t)(4 * quad + 3) * HW;
    float* __restrict__ o0 = out + (size_t)(4 * quad + 0) * (NA * NR);
    float* __restrict__ o1 = out + (size_t)(4 * quad + 1) * (NA * NR);
    float* __restrict__ o2 = out + (size_t)(4 * quad + 2) * (NA * NR);
    float* __restrict__ o3 = out + (size_t)(4 * quad + 3) * (NA * NR);

    // fast-axis indices owned by this lane (j = 0..3)
    const int fj0 = 2 * l;        // cols j=0,1
    const int fj2 = 2 * l + 128;  // cols j=2,3

    // ---- load persistent px tile: 8 scan x 4 fast x 4 img, f16 packed ----
    __half2 pxA[8][4], pxB[8][4];
    if (phase == 0) {
        // scan=y: row y=k0+k; fast=x at {2l,2l+1} and {2l+128,2l+129}
        #pragma unroll
        for (int k = 0; k < 8; ++k) {
            const int ro = (k0 + k) << 8;
            const float2 v0a = *(const float2*)(f0 + ro + fj0);
            const float2 v1a = *(const float2*)(f1 + ro + fj0);
            const float2 v2a = *(const float2*)(f2 + ro + fj0);
            const float2 v3a = *(const float2*)(f3 + ro + fj0);
            const float2 v0b = *(const float2*)(f0 + ro + fj2);
            const float2 v1b = *(const float2*)(f1 + ro + fj2);
            const float2 v2b = *(const float2*)(f2 + ro + fj2);
            const float2 v3b = *(const float2*)(f3 + ro + fj2);
            pxA[k][0] = __floats2half2_rn(v0a.x, v1a.x);
            pxB[k][0] = __floats2half2_rn(v2a.x, v3a.x);
            pxA[k][1] = __floats2half2_rn(v0a.y, v1a.y);
            pxB[k][1] = __floats2half2_rn(v2a.y, v3a.y);
            pxA[k][2] = __floats2half2_rn(v0b.x, v1b.x);
            pxB[k][2] = __floats2half2_rn(v2b.x, v3b.x);
            pxA[k][3] = __floats2half2_rn(v0b.y, v1b.y);
            pxB[k][3] = __floats2half2_rn(v2b.y, v3b.y);
        }
    } else {
        // scan=x: fast=y rows {2l,2l+1,2l+128,2l+129}; cols x=k0..k0+7
        #pragma unroll
        for (int j = 0; j < 4; ++j) {
            const int fr = (j < 2) ? (fj0 + j) : (fj2 + (j - 2));
            const int ro = fr << 8;
            const float4 q0 = *(const float4*)(f0 + ro + k0);
            const float4 q1 = *(const float4*)(f0 + ro + k0 + 4);
            const float4 r0 = *(const float4*)(f1 + ro + k0);
            const float4 r1 = *(const float4*)(f1 + ro + k0 + 4);
            const float4 s0 = *(const float4*)(f2 + ro + k0);
            const float4 s1 = *(const float4*)(f2 + ro + k0 + 4);
            const float4 t0 = *(const float4*)(f3 + ro + k0);
            const float4 t1 = *(const float4*)(f3 + ro + k0 + 4);
            pxA[0][j] = __floats2half2_rn(q0.x, r0.x);
            pxB[0][j] = __floats2half2_rn(s0.x, t0.x);
            pxA[1][j] = __floats2half2_rn(q0.y, r0.y);
            pxB[1][j] = __floats2half2_rn(s0.y, t0.y);
            pxA[2][j] = __floats2half2_rn(q0.z, r0.z);
            pxB[2][j] = __floats2half2_rn(s0.z, t0.z);
            pxA[3][j] = __floats2half2_rn(q0.w, r0.w);
            pxB[3][j] = __floats2half2_rn(s0.w, t0.w);
            pxA[4][j] = __floats2half2_rn(q1.x, r1.x);
            pxB[4][j] = __floats2half2_rn(s1.x, t1.x);
            pxA[5][j] = __floats2half2_rn(q1.y, r1.y);
            pxB[5][j] = __floats2half2_rn(s1.y, t1.y);
            pxA[6][j] = __floats2half2_rn(q1.z, r1.z);
            pxB[6][j] = __floats2half2_rn(s1.z, t1.z);
            pxA[7][j] = __floats2half2_rn(q1.w, r1.w);
            pxB[7][j] = __floats2half2_rn(s1.w, t1.w);
        }
    }

    const int nAng = phase ? 89 : 91;
    for (int aidx = 0; aidx < nAng; ++aidx) {
        {   // zero rows (bit pattern 0 == f16 zero)
            float2* z = (float2*)rows;
            for (int i = t; i < 16 * ROW_PAD; i += 1024)
                z[i] = make_float2(0.f, 0.f);
        }
        __syncthreads();

        const int a = phase ? (46 + aidx) : (aidx <= 45 ? aidx : aidx + 89);
        const unsigned int* wrow = win + ((size_t)a * NWIN + w) * 256;
        const uint2 u0 = *(const uint2*)(wrow + fj0);   // cols 2l, 2l+1
        const uint2 u1 = *(const uint2*)(wrow + fj2);   // cols 2l+128, 2l+129
        uint4 wq; wq.x = u0.x; wq.y = u0.y; wq.z = u1.x; wq.w = u1.y;
        h4* __restrict__ rp = rows + wv * ROW_PAD;
        if (phase && a > 90) walk_one<-1>(wq, pxA, pxB, rp);
        else                 walk_one<+1>(wq, pxA, pxB, rp);
        __syncthreads();

        // flush: thread t < 368 sums the 16 wave copies of bin t in f32 and
        // issues 4 contiguous global atomic adds (one per image). Exactly-2
        // commutative contributions per out element (two scan-halves).
        if (t < ROW_W) {
            float s0 = 0.f, s1 = 0.f, s2 = 0.f, s3 = 0.f;
            #pragma unroll
            for (int c2 = 0; c2 < 16; ++c2) {
                const h4 v = rows[c2 * ROW_PAD + t];
                s0 += __low2float(v.a); s1 += __high2float(v.a);
                s2 += __low2float(v.b); s3 += __high2float(v.b);
            }
            const size_t o = (size_t)a * NR + (RBASE + t);
            unsafeAtomicAdd(o0 + o, s0);
            unsafeAtomicAdd(o1 + o, s1);
            unsafeAtomicAdd(o2 + o, s2);
            unsafeAtomicAdd(o3 + o, s3);
        }
        __syncthreads();
    }
}

extern "C" void kernel_launch(void* const* d_in, const int* in_sizes, int n_in,
                              void* d_out, int out_size, void* d_ws, size_t ws_size,
                              hipStream_t stream) {
    const float* feat = (const float*)d_in[0];
    float* out = (float*)d_out;
    unsigned int* win = (unsigned int*)d_ws;

    const size_t win_bytes = (size_t)NA * NWIN * 256 * sizeof(unsigned int); // 5.9MB
    if (ws_size < win_bytes) return;

    const int n4 = out_size / 4;   // out_size = 512*180*723, divisible by 4
    hipLaunchKernelGGL(zero_out, dim3((n4 + 255) / 256), dim3(256), 0, stream,
                       (float4*)out, n4);
    hipLaunchKernelGGL(dht_win, dim3(NWIN, NA), dim3(256), 0, stream, win);
    hipLaunchKernelGGL(dht_main, dim3(NC / 4, 2, 2), dim3(1024), 0, stream,
                       feat, win, out);
}

// Round 22
// 985.039 us; speedup vs baseline: 1.1041x; 1.1041x over previous
//
#include <hip/hip_runtime.h>
#include <hip/hip_fp16.h>
#include <cmath>

// DHT: out[n,c,a,r] = sum over px (x,y) of feat[n,c,y,x],
//   r = rint((x-128)*cos(a deg) + (y-128)*sin(a deg)) + 361  (r in [180,542])
// feat[4,128,256,256] f32 -> out[4,128,180,723] f32.
//
// Locked-in findings:
//  R1-R4: LDS f32 atomicAdd ~per-lane serial -> never on hot path.
//  R5/R18: DS RMW race-free iff lanes' bins distinct PER INSTRUCTION; no
//    read-hoisting across lane-overlapping writes. R10: exec-mask poison.
//  R12/R15/R17/R20: SQ_LDS_BANK_CONFLICT = PORT-BYTE tax (prop. to bytes,
//    invariant to addresses, width, count). R16: occupancy != port BW.
//  R17 (846us): f16 4img/b64. R19 (813us, BEST): + dual-angle no-alias ILP.
//  R21 (1082us, CONFOUNDED): __launch_bounds__ cap 64 < px tile 64+misc ->
//    compiler REMATERIALIZED px loads per angle (FETCH 167MB->2.6GB,
//    VGPR=32). Never cap VGPR below the persistent tile.
//  R22: the clean occupancy test. 2 images/block as __half2 bins (px = 32
//    VGPR, fits 64-cap), CH=1, 23.5KB LDS, grid 1024 blocks -> 32 waves/CU
//    (8/SIMD). Port bytes/img-visit unchanged; instr count = R12 level
//    (neutral per R20). Tests: can TLP overlap the DS<->VALU chains?

#define NA 180
#define NR 723
#define HW 65536
#define NC 512
#define ROW_W 368       // bins rl = r-RBASE in [4,366]
#define ROW_PAD 368
#define RBASE 176
#define NWIN 32         // 8-px windows along the scan axis

__device__ __forceinline__ bool is_phase2(int a) { return a >= 46 && a <= 134; }

// ---------------------------------------------------------------------------
// win[a][w][fast] u32 = base bin at scan=8w (bits 0..15), step bits 16..22.
// Phase-1 (a in [0,45]u[135,179]): fast=x, scan=y. Phase-2 (a in [46,134]):
// fast=y, scan=x (sign flips at 90). fp64 non-fused + rint == np.round
// (validated R1-R21).
// ---------------------------------------------------------------------------
__global__ __launch_bounds__(256) void dht_win(unsigned int* __restrict__ win) {
    const int lane = threadIdx.x;
    const int w = blockIdx.x;
    const int a = blockIdx.y;
    const double theta = (double)a * (M_PI / 180.0);
    const double c = cos(theta), s = sin(theta);
    const bool p2 = is_phase2(a);
    int prev = 0;
    unsigned int word = 0;
    #pragma unroll
    for (int i = 0; i < 8; ++i) {
        const int k = w * 8 + i;
        const int x = p2 ? k : lane;
        const int y = p2 ? lane : k;
        const double rho = __dadd_rn(__dmul_rn((double)(x - 128), c),
                                     __dmul_rn((double)(y - 128), s));
        int r = (int)rint(rho) + 361;
        r = min(max(r, 0), NR - 1);
        if (i == 0) word = (unsigned int)r;
        else if (r != prev) word |= (1u << (15 + i));
        prev = r;
    }
    win[((size_t)a * NWIN + w) * 256 + lane] = word;
}

__global__ __launch_bounds__(256) void zero_out(float4* __restrict__ o, int n4) {
    const int i = blockIdx.x * 256 + threadIdx.x;
    if (i < n4) o[i] = make_float4(0.f, 0.f, 0.f, 0.f);
}

// Single-angle walk, __half2 bins (2 images). Strict per-visit read->add->
// write order; lanes 2 cols apart -> bins >= 1.414 apart per instruction
// -> race-free. Dense unconditional RMW stream.
template <int SGN>
__device__ __forceinline__ void walk_one(const uint4 wq,
                                         const __half2 (&px)[8][4],
                                         __half2* __restrict__ rp) {
    #pragma unroll
    for (int j = 0; j < 4; ++j) {
        const unsigned int wrd = (&wq.x)[j];
        int bin = (int)(wrd & 0xffffu) - RBASE;
        #pragma unroll
        for (int k = 0; k < 8; ++k) {
            if (k) bin += SGN * (int)((wrd >> (15 + k)) & 1u);
            rp[bin] = __hadd2(rp[bin], px[k][j]);
        }
    }
}

// ---------------------------------------------------------------------------
// Block = (image-pair, phase, scan-half). 1024 thr = 16 waves; wave wv owns
// scan window w = 16h+wv (8 scan lines); lane owns fast columns
// {2l, 2l+1, 2l+128, 2l+129} (j = 0..3). px = 32 __half2 VGPR (8 scan x
// 4 col x 2 img f16), loaded+converted ONCE, reused across all angles.
// rows[16 waves][ROW_PAD] __half2 = 23.5 KB -> wave-limited 2 blocks/CU
// = 32 waves (8/SIMD, max).
// ---------------------------------------------------------------------------
__global__ __launch_bounds__(1024, 8) void dht_main(const float* __restrict__ feat,
                                                    const unsigned int* __restrict__ win,
                                                    float* __restrict__ out) {
    __shared__ __half2 rows[16 * ROW_PAD];   // 23.5 KB, one angle at a time
    const int t = threadIdx.x;
    const int wv = t >> 6;
    const int l = t & 63;
    const int pair = blockIdx.x;
    const int phase = blockIdx.y;
    const int h = blockIdx.z;
    const int w = 16 * h + wv;          // scan window 0..31
    const int k0 = 8 * w;               // scan offset
    const float* __restrict__ f0 = feat + (size_t)(2 * pair) * HW;
    const float* __restrict__ f1 = feat + (size_t)(2 * pair + 1) * HW;
    float* __restrict__ o0 = out + (size_t)(2 * pair) * (NA * NR);
    float* __restrict__ o1 = out + (size_t)(2 * pair + 1) * (NA * NR);

    // fast-axis indices owned by this lane (j = 0..3)
    const int fj0 = 2 * l;        // cols j=0,1
    const int fj2 = 2 * l + 128;  // cols j=2,3

    // ---- load persistent px tile: 8 scan x 4 fast x 2 img, f16 packed ----
    __half2 px[8][4];               // {img0, img1} per (scan, col)
    if (phase == 0) {
        // scan=y: row y=k0+k; fast=x at {2l,2l+1} and {2l+128,2l+129}
        #pragma unroll
        for (int k = 0; k < 8; ++k) {
            const int ro = (k0 + k) << 8;
            const float2 a0 = *(const float2*)(f0 + ro + fj0);
            const float2 a1 = *(const float2*)(f0 + ro + fj2);
            const float2 b0 = *(const float2*)(f1 + ro + fj0);
            const float2 b1 = *(const float2*)(f1 + ro + fj2);
            px[k][0] = __floats2half2_rn(a0.x, b0.x);
            px[k][1] = __floats2half2_rn(a0.y, b0.y);
            px[k][2] = __floats2half2_rn(a1.x, b1.x);
            px[k][3] = __floats2half2_rn(a1.y, b1.y);
        }
    } else {
        // scan=x: fast=y rows {2l,2l+1,2l+128,2l+129}; cols x=k0..k0+7
        #pragma unroll
        for (int j = 0; j < 4; ++j) {
            const int fr = (j < 2) ? (fj0 + j) : (fj2 + (j - 2));
            const int ro = fr << 8;
            const float4 q0 = *(const float4*)(f0 + ro + k0);
            const float4 q1 = *(const float4*)(f0 + ro + k0 + 4);
            const float4 r0 = *(const float4*)(f1 + ro + k0);
            const float4 r1 = *(const float4*)(f1 + ro + k0 + 4);
            px[0][j] = __floats2half2_rn(q0.x, r0.x);
            px[1][j] = __floats2half2_rn(q0.y, r0.y);
            px[2][j] = __floats2half2_rn(q0.z, r0.z);
            px[3][j] = __floats2half2_rn(q0.w, r0.w);
            px[4][j] = __floats2half2_rn(q1.x, r1.x);
            px[5][j] = __floats2half2_rn(q1.y, r1.y);
            px[6][j] = __floats2half2_rn(q1.z, r1.z);
            px[7][j] = __floats2half2_rn(q1.w, r1.w);
        }
    }

    const int nAng = phase ? 89 : 91;
    for (int aidx = 0; aidx < nAng; ++aidx) {
        {   // zero rows (bit pattern 0 == f16 zero); u32 view
            unsigned int* z = (unsigned int*)rows;
            for (int i = t; i < 16 * ROW_PAD; i += 1024) z[i] = 0u;
        }
        __syncthreads();

        const int a = phase ? (46 + aidx) : (aidx <= 45 ? aidx : aidx + 89);
        const unsigned int* wrow = win + ((size_t)a * NWIN + w) * 256;
        const uint2 u0 = *(const uint2*)(wrow + fj0);   // cols 2l, 2l+1
        const uint2 u1 = *(const uint2*)(wrow + fj2);   // cols 2l+128, 2l+129
        uint4 wq; wq.x = u0.x; wq.y = u0.y; wq.z = u1.x; wq.w = u1.y;
        __half2* __restrict__ rp = rows + wv * ROW_PAD;
        if (phase && a > 90) walk_one<-1>(wq, px, rp);
        else                 walk_one<+1>(wq, px, rp);
        __syncthreads();

        // flush: thread t < 368 sums the 16 wave copies of bin t in f32,
        // 2 contiguous global atomic adds (one per image). Exactly-2
        // commutative contributions per out element (two scan-halves).
        if (t < ROW_W) {
            float s0 = 0.f, s1 = 0.f;
            #pragma unroll
            for (int c2 = 0; c2 < 16; ++c2) {
                const __half2 v = rows[c2 * ROW_PAD + t];
                s0 += __low2float(v);
                s1 += __high2float(v);
            }
            const size_t o = (size_t)a * NR + (RBASE + t);
            unsafeAtomicAdd(o0 + o, s0);
            unsafeAtomicAdd(o1 + o, s1);
        }
        __syncthreads();
    }
}

extern "C" void kernel_launch(void* const* d_in, const int* in_sizes, int n_in,
                              void* d_out, int out_size, void* d_ws, size_t ws_size,
                              hipStream_t stream) {
    const float* feat = (const float*)d_in[0];
    float* out = (float*)d_out;
    unsigned int* win = (unsigned int*)d_ws;

    const size_t win_bytes = (size_t)NA * NWIN * 256 * sizeof(unsigned int); // 5.9MB
    if (ws_size < win_bytes) return;

    const int n4 = out_size / 4;   // out_size = 512*180*723, divisible by 4
    hipLaunchKernelGGL(zero_out, dim3((n4 + 255) / 256), dim3(256), 0, stream,
                       (float4*)out, n4);
    hipLaunchKernelGGL(dht_win, dim3(NWIN, NA), dim3(256), 0, stream, win);
    hipLaunchKernelGGL(dht_main, dim3(NC / 2, 2, 2), dim3(1024), 0, stream,
                       feat, win, out);
}

// Round 23
// 816.241 us; speedup vs baseline: 1.3324x; 1.2068x over previous
//
#include <hip/hip_runtime.h>
#include <hip/hip_fp16.h>
#include <cmath>

// DHT: out[n,c,a,r] = sum over px (x,y) of feat[n,c,y,x],
//   r = rint((x-128)*cos(a deg) + (y-128)*sin(a deg)) + 361  (r in [180,542])
// feat[4,128,256,256] f32 -> out[4,128,180,723] f32.
//
// FINAL STRUCTURE (= R19, best at 813us). Complete finding ledger:
//  R1-R4 (~31ms): LDS f32 atomicAdd ~per-lane serial -> never on hot path.
//  R5: wave-private rows + program-ordered DS RMW, race-free iff concurrent
//    lanes' bins provably distinct PER INSTRUCTION (spacing >= 1.05 bins).
//  R6: image re-reads at >1 block/CU -> HBM-bound. R7: register-persistent
//    px across ALL angles (the 2x lever). R10: exec-masked DS RMW poison.
//  R8/R9/R13/R14/R15/R20: SQ_LDS_BANK_CONFLICT = PORT-BYTE tax, exactly
//    proportional to RMW bytes (R17 halved bytes -> halved counter),
//    invariant to addresses, swizzles, widths, instruction count.
//  R16/R22: occupancy cannot add port bandwidth; max TLP does NOT overlap
//    the DS<->VALU dependent chains (terms add serially at 4 AND 8 w/SIMD).
//  R17: f16 accumulators, 4 img per b64 RMW (846us). R18 (FAILED): read
//    batching races ACROSS lanes. R19: dual-angle chains in two separate
//    __shared__ objects (no-alias ILP, -33us) -> 813us.
//  R21: VGPR cap below persistent tile -> silent remat (FETCH 15x). 
//  Budget (cyc/CU): port 738K + tax 545K + zero/flush ~260K + VALU ~170K
//    serialization remnant ~= 1.95M measured. Port+tax are hardware floors
//    for any LDS-mediated scatter at f16 precision (min for 1.91 threshold).

#define NA 180
#define NR 723
#define HW 65536
#define NC 512
#define ROW_W 368       // bins rl = r-RBASE in [4,366]
#define ROW_PAD 368
#define RBASE 176
#define NWIN 32         // 8-px windows along the scan axis

__device__ __forceinline__ bool is_phase2(int a) { return a >= 46 && a <= 134; }

// 4 images packed per bin: .a = {img0,img1}, .b = {img2,img3}
struct __align__(8) h4 { __half2 a, b; };

// ---------------------------------------------------------------------------
// win[a][w][fast] u32 = base bin at scan=8w (bits 0..15), step bits 16..22.
// Phase-1 (a in [0,45]u[135,179]): fast=x, scan=y. Phase-2 (a in [46,134]):
// fast=y, scan=x (sign flips at 90). fp64 non-fused + rint == np.round.
// ---------------------------------------------------------------------------
__global__ __launch_bounds__(256) void dht_win(unsigned int* __restrict__ win) {
    const int lane = threadIdx.x;
    const int w = blockIdx.x;
    const int a = blockIdx.y;
    const double theta = (double)a * (M_PI / 180.0);
    const double c = cos(theta), s = sin(theta);
    const bool p2 = is_phase2(a);
    int prev = 0;
    unsigned int word = 0;
    #pragma unroll
    for (int i = 0; i < 8; ++i) {
        const int k = w * 8 + i;
        const int x = p2 ? k : lane;
        const int y = p2 ? lane : k;
        const double rho = __dadd_rn(__dmul_rn((double)(x - 128), c),
                                     __dmul_rn((double)(y - 128), s));
        int r = (int)rint(rho) + 361;
        r = min(max(r, 0), NR - 1);
        if (i == 0) word = (unsigned int)r;
        else if (r != prev) word |= (1u << (15 + i));
        prev = r;
    }
    win[((size_t)a * NWIN + w) * 256 + lane] = word;
}

__global__ __launch_bounds__(256) void zero_out(float4* __restrict__ o, int n4) {
    const int i = blockIdx.x * 256 + threadIdx.x;
    if (i < n4) o[i] = make_float4(0.f, 0.f, 0.f, 0.f);
}

// Single-angle walk (tail chunk). Strict per-visit read->add->write order;
// lanes 2 cols apart -> bins >= 1.414 apart per instruction -> race-free.
template <int SGN>
__device__ __forceinline__ void walk_one(const uint4 wq,
                                         const __half2 (&pxA)[8][4],
                                         const __half2 (&pxB)[8][4],
                                         h4* __restrict__ rp) {
    #pragma unroll
    for (int j = 0; j < 4; ++j) {
        const unsigned int wrd = (&wq.x)[j];
        int bin = (int)(wrd & 0xffffu) - RBASE;
        #pragma unroll
        for (int k = 0; k < 8; ++k) {
            if (k) bin += SGN * (int)((wrd >> (15 + k)) & 1u);
            h4 v = rp[bin];
            v.a = __hadd2(v.a, pxA[k][j]);
            v.b = __hadd2(v.b, pxB[k][j]);
            rp[bin] = v;
        }
    }
}

// Dual-angle walk into DISTINCT __shared__ objects (provable no-alias ->
// the two chains' reads batch per latency window). Per-chain order = R17.
template <int SGN0, int SGN1>
__device__ __forceinline__ void walk_dual(const uint4 wq0, const uint4 wq1,
                                          const __half2 (&pxA)[8][4],
                                          const __half2 (&pxB)[8][4],
                                          h4* __restrict__ rpA,
                                          h4* __restrict__ rpB) {
    #pragma unroll
    for (int j = 0; j < 4; ++j) {
        const unsigned int w0 = (&wq0.x)[j];
        const unsigned int w1 = (&wq1.x)[j];
        int b0 = (int)(w0 & 0xffffu) - RBASE;
        int b1 = (int)(w1 & 0xffffu) - RBASE;
        #pragma unroll
        for (int k = 0; k < 8; ++k) {
            if (k) {
                b0 += SGN0 * (int)((w0 >> (15 + k)) & 1u);
                b1 += SGN1 * (int)((w1 >> (15 + k)) & 1u);
            }
            h4 vA = rpA[b0];
            h4 vB = rpB[b1];
            vA.a = __hadd2(vA.a, pxA[k][j]);
            vA.b = __hadd2(vA.b, pxB[k][j]);
            vB.a = __hadd2(vB.a, pxA[k][j]);
            vB.b = __hadd2(vB.b, pxB[k][j]);
            rpA[b0] = vA;
            rpB[b1] = vB;
        }
    }
}

// ---------------------------------------------------------------------------
// Block = (image-quad, phase, scan-half). 1024 thr = 16 waves; wave wv owns
// scan window w = 16h+wv (8 scan lines); lane owns fast columns
// {2l, 2l+1, 2l+128, 2l+129} (j = 0..3). px as __half2 pairs, loaded +
// converted ONCE, reused across all angles of the phase.
// rowsA/rowsB[16 waves][ROW_PAD] h4 = 47.1 KB each -> 94 KB, 1 block/CU.
// ---------------------------------------------------------------------------
__global__ __launch_bounds__(1024, 4) void dht_main(const float* __restrict__ feat,
                                                    const unsigned int* __restrict__ win,
                                                    float* __restrict__ out) {
    __shared__ h4 rowsA[16 * ROW_PAD];   // angle cb+0 of each chunk
    __shared__ h4 rowsB[16 * ROW_PAD];   // angle cb+1 of each chunk
    const int t = threadIdx.x;
    const int wv = t >> 6;
    const int l = t & 63;
    const int quad = blockIdx.x;
    const int phase = blockIdx.y;
    const int h = blockIdx.z;
    const int w = 16 * h + wv;          // scan window 0..31
    const int k0 = 8 * w;               // scan offset
    const float* __restrict__ f0 = feat + (size_t)(4 * quad + 0) * HW;
    const float* __restrict__ f1 = feat + (size_t)(4 * quad + 1) * HW;
    const float* __restrict__ f2 = feat + (size_t)(4 * quad + 2) * HW;
    const float* __restrict__ f3 = feat + (size_t)(4 * quad + 3) * HW;
    float* __restrict__ o0 = out + (size_t)(4 * quad + 0) * (NA * NR);
    float* __restrict__ o1 = out + (size_t)(4 * quad + 1) * (NA * NR);
    float* __restrict__ o2 = out + (size_t)(4 * quad + 2) * (NA * NR);
    float* __restrict__ o3 = out + (size_t)(4 * quad + 3) * (NA * NR);

    // fast-axis indices owned by this lane (j = 0..3)
    const int fj0 = 2 * l;        // cols j=0,1
    const int fj2 = 2 * l + 128;  // cols j=2,3

    // ---- load persistent px tile: 8 scan x 4 fast x 4 img, f16 packed ----
    __half2 pxA[8][4], pxB[8][4];
    if (phase == 0) {
        // scan=y: row y=k0+k; fast=x at {2l,2l+1} and {2l+128,2l+129}
        #pragma unroll
        for (int k = 0; k < 8; ++k) {
            const int ro = (k0 + k) << 8;
            const float2 v0a = *(const float2*)(f0 + ro + fj0);
            const float2 v1a = *(const float2*)(f1 + ro + fj0);
            const float2 v2a = *(const float2*)(f2 + ro + fj0);
            const float2 v3a = *(const float2*)(f3 + ro + fj0);
            const float2 v0b = *(const float2*)(f0 + ro + fj2);
            const float2 v1b = *(const float2*)(f1 + ro + fj2);
            const float2 v2b = *(const float2*)(f2 + ro + fj2);
            const float2 v3b = *(const float2*)(f3 + ro + fj2);
            pxA[k][0] = __floats2half2_rn(v0a.x, v1a.x);
            pxB[k][0] = __floats2half2_rn(v2a.x, v3a.x);
            pxA[k][1] = __floats2half2_rn(v0a.y, v1a.y);
            pxB[k][1] = __floats2half2_rn(v2a.y, v3a.y);
            pxA[k][2] = __floats2half2_rn(v0b.x, v1b.x);
            pxB[k][2] = __floats2half2_rn(v2b.x, v3b.x);
            pxA[k][3] = __floats2half2_rn(v0b.y, v1b.y);
            pxB[k][3] = __floats2half2_rn(v2b.y, v3b.y);
        }
    } else {
        // scan=x: fast=y rows {2l,2l+1,2l+128,2l+129}; cols x=k0..k0+7
        #pragma unroll
        for (int j = 0; j < 4; ++j) {
            const int fr = (j < 2) ? (fj0 + j) : (fj2 + (j - 2));
            const int ro = fr << 8;
            const float4 q0 = *(const float4*)(f0 + ro + k0);
            const float4 q1 = *(const float4*)(f0 + ro + k0 + 4);
            const float4 r0 = *(const float4*)(f1 + ro + k0);
            const float4 r1 = *(const float4*)(f1 + ro + k0 + 4);
            const float4 s0 = *(const float4*)(f2 + ro + k0);
            const float4 s1 = *(const float4*)(f2 + ro + k0 + 4);
            const float4 t0 = *(const float4*)(f3 + ro + k0);
            const float4 t1 = *(const float4*)(f3 + ro + k0 + 4);
            pxA[0][j] = __floats2half2_rn(q0.x, r0.x);
            pxB[0][j] = __floats2half2_rn(s0.x, t0.x);
            pxA[1][j] = __floats2half2_rn(q0.y, r0.y);
            pxB[1][j] = __floats2half2_rn(s0.y, t0.y);
            pxA[2][j] = __floats2half2_rn(q0.z, r0.z);
            pxB[2][j] = __floats2half2_rn(s0.z, t0.z);
            pxA[3][j] = __floats2half2_rn(q0.w, r0.w);
            pxB[3][j] = __floats2half2_rn(s0.w, t0.w);
            pxA[4][j] = __floats2half2_rn(q1.x, r1.x);
            pxB[4][j] = __floats2half2_rn(s1.x, t1.x);
            pxA[5][j] = __floats2half2_rn(q1.y, r1.y);
            pxB[5][j] = __floats2half2_rn(s1.y, t1.y);
            pxA[6][j] = __floats2half2_rn(q1.z, r1.z);
            pxB[6][j] = __floats2half2_rn(s1.z, t1.z);
            pxA[7][j] = __floats2half2_rn(q1.w, r1.w);
            pxB[7][j] = __floats2half2_rn(s1.w, t1.w);
        }
    }

    const int nAng = phase ? 89 : 91;   // both odd: pairs + one tail angle
    for (int cb = 0; cb < nAng; cb += 2) {
        const int cn = min(2, nAng - cb);
        {   // zero both copies (bit pattern 0 == f16 zero)
            float2* zA = (float2*)rowsA;
            float2* zB = (float2*)rowsB;
            for (int i = t; i < 16 * ROW_PAD; i += 1024) {
                zA[i] = make_float2(0.f, 0.f);
                zB[i] = make_float2(0.f, 0.f);
            }
        }
        __syncthreads();

        const int a0 = phase ? (46 + cb) : (cb <= 45 ? cb : cb + 89);
        h4* __restrict__ rpA = rowsA + wv * ROW_PAD;
        if (cn == 2) {
            const int ax1 = cb + 1;
            const int a1 = phase ? (46 + ax1) : (ax1 <= 45 ? ax1 : ax1 + 89);
            const unsigned int* wr0 = win + ((size_t)a0 * NWIN + w) * 256;
            const unsigned int* wr1 = win + ((size_t)a1 * NWIN + w) * 256;
            const uint2 p00 = *(const uint2*)(wr0 + fj0);
            const uint2 p01 = *(const uint2*)(wr0 + fj2);
            const uint2 p10 = *(const uint2*)(wr1 + fj0);
            const uint2 p11 = *(const uint2*)(wr1 + fj2);
            uint4 wq0; wq0.x = p00.x; wq0.y = p00.y; wq0.z = p01.x; wq0.w = p01.y;
            uint4 wq1; wq1.x = p10.x; wq1.y = p10.y; wq1.z = p11.x; wq1.w = p11.y;
            h4* __restrict__ rpB = rowsB + wv * ROW_PAD;
            if (!phase || a1 <= 90)
                walk_dual<+1, +1>(wq0, wq1, pxA, pxB, rpA, rpB);
            else if (a0 > 90)
                walk_dual<-1, -1>(wq0, wq1, pxA, pxB, rpA, rpB);
            else
                walk_dual<+1, -1>(wq0, wq1, pxA, pxB, rpA, rpB);
        } else {
            const unsigned int* wr0 = win + ((size_t)a0 * NWIN + w) * 256;
            const uint2 p00 = *(const uint2*)(wr0 + fj0);
            const uint2 p01 = *(const uint2*)(wr0 + fj2);
            uint4 wq0; wq0.x = p00.x; wq0.y = p00.y; wq0.z = p01.x; wq0.w = p01.y;
            if (phase && a0 > 90) walk_one<-1>(wq0, pxA, pxB, rpA);
            else                  walk_one<+1>(wq0, pxA, pxB, rpA);
        }
        __syncthreads();

        // flush: sum 16 wave copies in f32 (al=0 from rowsA, al=1 rowsB);
        // lanes iterate rl contiguously -> contiguous global atomics.
        // Exactly-2 commutative contributions per out element -> deterministic.
        for (int i = t; i < cn * ROW_W; i += 1024) {
            const int al = i / ROW_W;
            const int rl = i - al * ROW_W;
            const h4* __restrict__ src = al ? rowsB : rowsA;
            float s0 = 0.f, s1 = 0.f, s2 = 0.f, s3 = 0.f;
            #pragma unroll
            for (int c2 = 0; c2 < 16; ++c2) {
                const h4 v = src[c2 * ROW_PAD + rl];
                s0 += __low2float(v.a); s1 += __high2float(v.a);
                s2 += __low2float(v.b); s3 += __high2float(v.b);
            }
            const int aidx = cb + al;
            const int a = phase ? (46 + aidx) : (aidx <= 45 ? aidx : aidx + 89);
            const size_t o = (size_t)a * NR + (RBASE + rl);
            unsafeAtomicAdd(o0 + o, s0);
            unsafeAtomicAdd(o1 + o, s1);
            unsafeAtomicAdd(o2 + o, s2);
            unsafeAtomicAdd(o3 + o, s3);
        }
        __syncthreads();
    }
}

extern "C" void kernel_launch(void* const* d_in, const int* in_sizes, int n_in,
                              void* d_out, int out_size, void* d_ws, size_t ws_size,
                              hipStream_t stream) {
    const float* feat = (const float*)d_in[0];
    float* out = (float*)d_out;
    unsigned int* win = (unsigned int*)d_ws;

    const size_t win_bytes = (size_t)NA * NWIN * 256 * sizeof(unsigned int); // 5.9MB
    if (ws_size < win_bytes) return;

    const int n4 = out_size / 4;   // out_size = 512*180*723, divisible by 4
    hipLaunchKernelGGL(zero_out, dim3((n4 + 255) / 256), dim3(256), 0, stream,
                       (float4*)out, n4);
    hipLaunchKernelGGL(dht_win, dim3(NWIN, NA), dim3(256), 0, stream, win);
    hipLaunchKernelGGL(dht_main, dim3(NC / 4, 2, 2), dim3(1024), 0, stream,
                       feat, win, out);
}